// Round 1
// baseline (2370.812 us; speedup 1.0000x reference)
//
#include <hip/hip_runtime.h>

// ---------------------------------------------------------------------------
// 2-layer hetero GraphSAGE (PyG SAGEConv, mean aggr) on bipartite user<->item.
//   h_item = relu(mean_ui(x_user) @ W1l_ui^T + b1_ui + x_item @ W1r_ui^T)
//   h_user = relu(mean_iu(x_item) @ W1l_iu^T + b1_iu + x_user @ W1r_iu^T)
//   out_item = mean_ui(h_user) @ W2l_ui^T + b2_ui + h_item @ W2r_ui^T
//   out_user = mean_iu(h_item) @ W2l_iu^T + b2_iu + h_user @ W2r_iu^T
// d_out = [out_user | out_item] fp32.
//
// Strategy: build CSR per edge-type ONCE (reused by both layers), then one
// fused kernel per conv: pull-mean aggregation (no float atomics) + register
// blocked GEMM reading pre-transposed (k-major) weights from L2.
// ---------------------------------------------------------------------------

constexpr int HDIM = 256;

// ---------------- CSR build ----------------

__global__ void hist_kernel(const int* __restrict__ dst, int n, int* __restrict__ cnt) {
    int i = blockIdx.x * 256 + threadIdx.x;
    if (i < n) atomicAdd(&cnt[dst[i]], 1);
}

__global__ void block_reduce_kernel(const int* __restrict__ cnt, int n, int* __restrict__ sums) {
    __shared__ int sdata[256];
    int b = blockIdx.x, t = threadIdx.x;
    int v = 0;
#pragma unroll
    for (int j = 0; j < 4; j++) {
        int idx = b * 1024 + j * 256 + t;
        if (idx < n) v += cnt[idx];
    }
    sdata[t] = v;
    __syncthreads();
    for (int s = 128; s > 0; s >>= 1) {
        if (t < s) sdata[t] += sdata[t + s];
        __syncthreads();
    }
    if (t == 0) sums[b] = sdata[0];
}

__global__ void scan_sums_kernel(const int* __restrict__ sums, int* __restrict__ offs, int B) {
    if (blockIdx.x == 0 && threadIdx.x == 0) {
        int a = 0;
        for (int i = 0; i < B; i++) { offs[i] = a; a += sums[i]; }
    }
}

// Hillis-Steele inclusive scan per 1024-block, converted to exclusive + block offset.
// cnt and cursor may alias (each index read+written only by its own thread).
__global__ void block_scan_write_kernel(const int* cnt, int n, const int* __restrict__ offs,
                                        int* __restrict__ rp, int* cursor, int total) {
    __shared__ int sdata[1024];
    int b = blockIdx.x, t = threadIdx.x;
    int idx = b * 1024 + t;
    int v = (idx < n) ? cnt[idx] : 0;
    sdata[t] = v;
    __syncthreads();
    for (int s = 1; s < 1024; s <<= 1) {
        int x = (t >= s) ? sdata[t - s] : 0;
        __syncthreads();
        sdata[t] += x;
        __syncthreads();
    }
    if (idx < n) {
        int excl = sdata[t] - v + offs[b];
        rp[idx] = excl;
        cursor[idx] = excl;
    }
    if (b == 0 && t == 0) rp[n] = total;
}

__global__ void fill_kernel(const int* __restrict__ src, const int* __restrict__ dst, int n,
                            int* cursor, int* __restrict__ col) {
    int i = blockIdx.x * 256 + threadIdx.x;
    if (i < n) {
        int p = atomicAdd(&cursor[dst[i]], 1);
        col[p] = src[i];
    }
}

// W [H][K] row-major -> Wt [K][H] (k-major) so GEMM reads are h-contiguous.
__global__ void transpose_w_kernel(const float* __restrict__ W, float* __restrict__ Wt,
                                   int K, int n) {
    int i = blockIdx.x * 256 + threadIdx.x;
    if (i < n) {
        int h = i / K, k = i - h * K;
        Wt[k * HDIM + h] = W[i];
    }
}

// ---------------- fused SAGE conv ----------------
// Block: 256 threads, TI=16 dst rows x 256 outputs. Thread (hq = tid&63,
// iq = tid>>6) computes a 4x4 (i x h) register tile.

template <int K>
__device__ __forceinline__ void gemm_part(const float (*At)[20], const float* __restrict__ Wt,
                                          int hq, int iq, float acc[4][4]) {
    const float4* W4 = (const float4*)Wt;  // [K][64] float4
#pragma unroll 4
    for (int k = 0; k < K; k++) {
        float4 w = W4[k * 64 + hq];                       // L2-resident, wave-contiguous 1KB
        float4 a = *(const float4*)(&At[k][iq * 4]);      // LDS broadcast (same addr per wave)
        acc[0][0] += a.x * w.x; acc[0][1] += a.x * w.y; acc[0][2] += a.x * w.z; acc[0][3] += a.x * w.w;
        acc[1][0] += a.y * w.x; acc[1][1] += a.y * w.y; acc[1][2] += a.y * w.z; acc[1][3] += a.y * w.w;
        acc[2][0] += a.z * w.x; acc[2][1] += a.z * w.y; acc[2][2] += a.z * w.z; acc[2][3] += a.z * w.w;
        acc[3][0] += a.w * w.x; acc[3][1] += a.w * w.y; acc[3][2] += a.w * w.z; acc[3][3] += a.w * w.w;
    }
}

template <int KS, int KD, bool RELU>
__global__ __launch_bounds__(256)
void sage_layer(const float* __restrict__ x_src, const float* __restrict__ x_dst,
                const int* __restrict__ rp, const int* __restrict__ col,
                const float* __restrict__ Wlt, const float* __restrict__ bias,
                const float* __restrict__ Wrt, float* __restrict__ out, int n_dst) {
    constexpr int TI = 16;
    constexpr int KMAX = (KS > KD) ? KS : KD;
    // Row pad to 20 floats: keeps 16B alignment for float4 reads, spreads the
    // (rare) column-writes across 8 banks instead of 2.
    __shared__ __align__(16) float At[KMAX][20];

    const int tid = threadIdx.x;
    const int row0 = blockIdx.x * TI;
    const int hq = tid & 63;
    const int iq = tid >> 6;

    float acc[4][4];
#pragma unroll
    for (int i = 0; i < 4; i++)
#pragma unroll
        for (int j = 0; j < 4; j++) acc[i][j] = 0.f;

    // ---- phase 1: pull-mean aggregate into At[k][i] ----
    {
        constexpr int G = 256 / KS;  // rows processed in parallel (1,2,4)
        const int g = tid / KS, f = tid % KS;
#pragma unroll
        for (int i0 = 0; i0 < TI; i0 += G) {
            int i = i0 + g, d = row0 + i;
            float s = 0.f;
            if (d < n_dst) {
                int e0 = rp[d], e1 = rp[d + 1];
                float s0 = 0.f, s1 = 0.f, s2 = 0.f, s3 = 0.f;
                int e = e0;
                for (; e + 4 <= e1; e += 4) {  // 4 independent loads in flight
                    int c0 = col[e], c1 = col[e + 1], c2 = col[e + 2], c3 = col[e + 3];
                    s0 += x_src[(size_t)c0 * KS + f];
                    s1 += x_src[(size_t)c1 * KS + f];
                    s2 += x_src[(size_t)c2 * KS + f];
                    s3 += x_src[(size_t)c3 * KS + f];
                }
                for (; e < e1; ++e) s0 += x_src[(size_t)col[e] * KS + f];
                s = (s0 + s1) + (s2 + s3);
                int deg = e1 - e0;
                s = (deg > 0) ? s * (1.0f / (float)deg) : 0.f;
            }
            At[f][i] = s;
        }
    }
    __syncthreads();

    // ---- phase 2: acc += mean . Wl^T ----
    gemm_part<KS>(At, Wlt, hq, iq, acc);
    __syncthreads();

    // ---- phase 3: stage root (x_dst) tile ----
    {
        constexpr int G = 256 / KD;
        const int g = tid / KD, f = tid % KD;
#pragma unroll
        for (int i0 = 0; i0 < TI; i0 += G) {
            int i = i0 + g, d = row0 + i;
            At[f][i] = (d < n_dst) ? x_dst[(size_t)d * KD + f] : 0.f;
        }
    }
    __syncthreads();

    // ---- phase 4: acc += root . Wr^T ----
    gemm_part<KD>(At, Wrt, hq, iq, acc);

    // ---- epilogue: + bias, optional relu, float4 store ----
    float4 bv = ((const float4*)bias)[hq];
#pragma unroll
    for (int ii = 0; ii < 4; ii++) {
        int d = row0 + iq * 4 + ii;
        if (d >= n_dst) continue;
        float4 o;
        o.x = acc[ii][0] + bv.x;
        o.y = acc[ii][1] + bv.y;
        o.z = acc[ii][2] + bv.z;
        o.w = acc[ii][3] + bv.w;
        if (RELU) {
            o.x = fmaxf(o.x, 0.f); o.y = fmaxf(o.y, 0.f);
            o.z = fmaxf(o.z, 0.f); o.w = fmaxf(o.w, 0.f);
        }
        *(float4*)&out[(size_t)d * HDIM + hq * 4] = o;
    }
}

// ---------------- host ----------------

extern "C" void kernel_launch(void* const* d_in, const int* in_sizes, int n_in,
                              void* d_out, int out_size, void* d_ws, size_t ws_size,
                              hipStream_t stream) {
    const float* x_user = (const float*)d_in[0];
    const float* x_item = (const float*)d_in[1];
    const int* eui_src = (const int*)d_in[2];
    const int* eui_dst = (const int*)d_in[3];
    const int* eiu_src = (const int*)d_in[4];
    const int* eiu_dst = (const int*)d_in[5];
    const float* W1l_ui = (const float*)d_in[6];
    const float* b1_ui  = (const float*)d_in[7];
    const float* W1r_ui = (const float*)d_in[8];
    const float* W1l_iu = (const float*)d_in[9];
    const float* b1_iu  = (const float*)d_in[10];
    const float* W1r_iu = (const float*)d_in[11];
    const float* W2l_ui = (const float*)d_in[12];
    const float* b2_ui  = (const float*)d_in[13];
    const float* W2r_ui = (const float*)d_in[14];
    const float* W2l_iu = (const float*)d_in[15];
    const float* b2_iu  = (const float*)d_in[16];
    const float* W2r_iu = (const float*)d_in[17];

    const int DU = 128, DI = 64;
    const int NU = in_sizes[0] / DU;   // 100000
    const int NI = in_sizes[1] / DI;   // 50000
    const int E  = in_sizes[2];        // 1600000

    // ---- carve workspace (256B aligned) ----
    char* w = (char*)d_ws;
    auto carve = [&](size_t bytes) -> void* {
        void* p = (void*)w;
        w += (bytes + 255) & ~(size_t)255;
        return p;
    };
    int* cnt_i  = (int*)carve((size_t)NI * 4);        // also CSR fill cursor
    int* cnt_u  = (int*)carve((size_t)NU * 4);
    int* rp_i   = (int*)carve((size_t)(NI + 1) * 4);
    int* rp_u   = (int*)carve((size_t)(NU + 1) * 4);
    int* col_ui = (int*)carve((size_t)E * 4);         // user srcs grouped by item dst
    int* col_iu = (int*)carve((size_t)E * 4);         // item srcs grouped by user dst
    int* bsum   = (int*)carve(1024 * 4);
    int* boff   = (int*)carve(1024 * 4);
    float* W1l_ui_t = (float*)carve((size_t)HDIM * DU * 4);
    float* W1r_ui_t = (float*)carve((size_t)HDIM * DI * 4);
    float* W1l_iu_t = (float*)carve((size_t)HDIM * DI * 4);
    float* W1r_iu_t = (float*)carve((size_t)HDIM * DU * 4);
    float* W2l_ui_t = (float*)carve((size_t)HDIM * HDIM * 4);
    float* W2r_ui_t = (float*)carve((size_t)HDIM * HDIM * 4);
    float* W2l_iu_t = (float*)carve((size_t)HDIM * HDIM * 4);
    float* W2r_iu_t = (float*)carve((size_t)HDIM * HDIM * 4);
    float* h_item = (float*)carve((size_t)NI * HDIM * 4);   // 51.2 MB
    float* h_user = (float*)carve((size_t)NU * HDIM * 4);   // 102.4 MB

    float* out_user = (float*)d_out;                        // [NU][256]
    float* out_item = (float*)d_out + (size_t)NU * HDIM;    // [NI][256]

    // ---- CSR build (once; both layers reuse it) ----
    hipMemsetAsync(cnt_i, 0, (size_t)NI * 4, stream);
    hipMemsetAsync(cnt_u, 0, (size_t)NU * 4, stream);

    int egrid = (E + 255) / 256;
    hist_kernel<<<egrid, 256, 0, stream>>>(eui_dst, E, cnt_i);
    hist_kernel<<<egrid, 256, 0, stream>>>(eiu_dst, E, cnt_u);

    int Bi = (NI + 1023) / 1024, Bu = (NU + 1023) / 1024;
    block_reduce_kernel<<<Bi, 256, 0, stream>>>(cnt_i, NI, bsum);
    scan_sums_kernel<<<1, 64, 0, stream>>>(bsum, boff, Bi);
    block_scan_write_kernel<<<Bi, 1024, 0, stream>>>(cnt_i, NI, boff, rp_i, cnt_i, E);
    fill_kernel<<<egrid, 256, 0, stream>>>(eui_src, eui_dst, E, cnt_i, col_ui);

    block_reduce_kernel<<<Bu, 256, 0, stream>>>(cnt_u, NU, bsum);
    scan_sums_kernel<<<1, 64, 0, stream>>>(bsum, boff, Bu);
    block_scan_write_kernel<<<Bu, 1024, 0, stream>>>(cnt_u, NU, boff, rp_u, cnt_u, E);
    fill_kernel<<<egrid, 256, 0, stream>>>(eiu_src, eiu_dst, E, cnt_u, col_iu);

    // ---- pre-transpose weights to k-major ----
    auto tw = [&](const float* W, float* Wt, int K) {
        int n = HDIM * K;
        transpose_w_kernel<<<(n + 255) / 256, 256, 0, stream>>>(W, Wt, K, n);
    };
    tw(W1l_ui, W1l_ui_t, DU);
    tw(W1r_ui, W1r_ui_t, DI);
    tw(W1l_iu, W1l_iu_t, DI);
    tw(W1r_iu, W1r_iu_t, DU);
    tw(W2l_ui, W2l_ui_t, HDIM);
    tw(W2r_ui, W2r_ui_t, HDIM);
    tw(W2l_iu, W2l_iu_t, HDIM);
    tw(W2r_iu, W2r_iu_t, HDIM);

    // ---- layer 1 (relu) ----
    sage_layer<128, 64, true><<<(NI + 15) / 16, 256, 0, stream>>>(
        x_user, x_item, rp_i, col_ui, W1l_ui_t, b1_ui, W1r_ui_t, h_item, NI);
    sage_layer<64, 128, true><<<(NU + 15) / 16, 256, 0, stream>>>(
        x_item, x_user, rp_u, col_iu, W1l_iu_t, b1_iu, W1r_iu_t, h_user, NU);

    // ---- layer 2 (no relu) -> d_out ----
    sage_layer<256, 256, false><<<(NI + 15) / 16, 256, 0, stream>>>(
        h_user, h_item, rp_i, col_ui, W2l_ui_t, b2_ui, W2r_ui_t, out_item, NI);
    sage_layer<256, 256, false><<<(NU + 15) / 16, 256, 0, stream>>>(
        h_item, h_user, rp_u, col_iu, W2l_iu_t, b2_iu, W2r_iu_t, out_user, NU);
}

// Round 2
// 1475.812 us; speedup vs baseline: 1.6064x; 1.6064x over previous
//
#include <hip/hip_runtime.h>

// ---------------------------------------------------------------------------
// 2-layer hetero GraphSAGE, bipartite user<->item, H=256.
// Round 2: split aggregation from GEMM; bf16 everywhere internal; MFMA GEMMs.
//   convert x,W -> bf16
//   A_i = mean_ui(x_user_bf); A_u = mean_iu(x_item_bf)          [agg kernels]
//   h_item = relu(A_i@W1l^T + b + x_item@W1r^T)  (bf16 out)     [MFMA gemm]
//   h_user = relu(A_u@W1l^T + b + x_user@W1r^T)  (bf16 out)
//   B_i = mean_ui(h_user); B_u = mean_iu(h_item)
//   out_item = B_i@W2l^T + b + h_item@W2r^T      (fp32 out)
//   out_user = B_u@W2l^T + b + h_user@W2r^T
// ---------------------------------------------------------------------------

typedef unsigned short u16;
typedef unsigned int u32;
typedef short bf16x8 __attribute__((ext_vector_type(8)));   // 8 bf16 (4 VGPRs)
typedef float f32x4 __attribute__((ext_vector_type(4)));    // MFMA acc

constexpr int HDIM = 256;

// ---------------- bf16 helpers ----------------

__device__ __forceinline__ float lo2f(u32 v) { union { u32 i; float f; } x; x.i = v << 16; return x.f; }
__device__ __forceinline__ float hi2f(u32 v) { union { u32 i; float f; } x; x.i = v & 0xffff0000u; return x.f; }
__device__ __forceinline__ float bf2f(u16 v) { union { u32 i; float f; } x; x.i = ((u32)v) << 16; return x.f; }
__device__ __forceinline__ u16 f2bf(float f) {  // RNE
    union { float f; u32 i; } x; x.f = f;
    return (u16)((x.i + 0x7fffu + ((x.i >> 16) & 1u)) >> 16);
}
__device__ __forceinline__ u32 pack2(float a, float b) {
    return (u32)f2bf(a) | ((u32)f2bf(b) << 16);
}

// ---------------- CSR build (unchanged from round 1) ----------------

__global__ void hist_kernel(const int* __restrict__ dst, int n, int* __restrict__ cnt) {
    int i = blockIdx.x * 256 + threadIdx.x;
    if (i < n) atomicAdd(&cnt[dst[i]], 1);
}

__global__ void block_reduce_kernel(const int* __restrict__ cnt, int n, int* __restrict__ sums) {
    __shared__ int sdata[256];
    int b = blockIdx.x, t = threadIdx.x;
    int v = 0;
#pragma unroll
    for (int j = 0; j < 4; j++) {
        int idx = b * 1024 + j * 256 + t;
        if (idx < n) v += cnt[idx];
    }
    sdata[t] = v;
    __syncthreads();
    for (int s = 128; s > 0; s >>= 1) {
        if (t < s) sdata[t] += sdata[t + s];
        __syncthreads();
    }
    if (t == 0) sums[b] = sdata[0];
}

__global__ void scan_sums_kernel(const int* __restrict__ sums, int* __restrict__ offs, int B) {
    if (blockIdx.x == 0 && threadIdx.x == 0) {
        int a = 0;
        for (int i = 0; i < B; i++) { offs[i] = a; a += sums[i]; }
    }
}

__global__ void block_scan_write_kernel(const int* cnt, int n, const int* __restrict__ offs,
                                        int* __restrict__ rp, int* cursor, int total) {
    __shared__ int sdata[1024];
    int b = blockIdx.x, t = threadIdx.x;
    int idx = b * 1024 + t;
    int v = (idx < n) ? cnt[idx] : 0;
    sdata[t] = v;
    __syncthreads();
    for (int s = 1; s < 1024; s <<= 1) {
        int x = (t >= s) ? sdata[t - s] : 0;
        __syncthreads();
        sdata[t] += x;
        __syncthreads();
    }
    if (idx < n) {
        int excl = sdata[t] - v + offs[b];
        rp[idx] = excl;
        cursor[idx] = excl;
    }
    if (b == 0 && t == 0) rp[n] = total;
}

__global__ void fill_kernel(const int* __restrict__ src, const int* __restrict__ dst, int n,
                            int* cursor, int* __restrict__ col) {
    int i = blockIdx.x * 256 + threadIdx.x;
    if (i < n) {
        int p = atomicAdd(&cursor[dst[i]], 1);
        col[p] = src[i];
    }
}

// ---------------- fp32 -> bf16 convert (n must be multiple of 4) ----------------

__global__ void f32_to_bf16_kernel(const float* __restrict__ in, u16* __restrict__ out, int n4) {
    int i = blockIdx.x * 256 + threadIdx.x;
    if (i < n4) {
        float4 v = ((const float4*)in)[i];
        ((uint2*)out)[i] = make_uint2(pack2(v.x, v.y), pack2(v.z, v.w));
    }
}

// ---------------- mean aggregation: 1 wave per dst row ----------------
// src bf16 [n_src x F], out bf16 [n_dst x F]. fp32 accumulate, RNE to bf16.

template <int F>
__global__ __launch_bounds__(256) void agg_mean(const u16* __restrict__ src,
                                                const int* __restrict__ rp,
                                                const int* __restrict__ col,
                                                u16* __restrict__ out, int n_dst) {
    constexpr int VE = F / 64;  // bf16 per lane: 4 / 2 / 1
    const int lane = threadIdx.x & 63;
    const int d = blockIdx.x * 4 + (threadIdx.x >> 6);
    if (d >= n_dst) return;
    const int e0 = rp[d], e1 = rp[d + 1];
    float a0 = 0.f, a1 = 0.f, a2 = 0.f, a3 = 0.f;
    const size_t lo = (size_t)lane * VE;

    auto add = [&](int c) {
        const u16* p = src + (size_t)c * F + lo;
        if (VE == 4) {
            uint2 v = *(const uint2*)p;
            a0 += lo2f(v.x); a1 += hi2f(v.x); a2 += lo2f(v.y); a3 += hi2f(v.y);
        } else if (VE == 2) {
            u32 v = *(const u32*)p;
            a0 += lo2f(v); a1 += hi2f(v);
        } else {
            a0 += bf2f(*p);
        }
    };

    int e = e0;
    for (; e + 4 <= e1; e += 4) {  // 4 independent row-loads in flight
        int c0 = col[e], c1 = col[e + 1], c2 = col[e + 2], c3 = col[e + 3];
        add(c0); add(c1); add(c2); add(c3);
    }
    for (; e < e1; e++) add(col[e]);

    int deg = e1 - e0;
    float inv = (deg > 0) ? 1.f / (float)deg : 0.f;
    a0 *= inv; a1 *= inv; a2 *= inv; a3 *= inv;

    u16* q = out + (size_t)d * F + lo;
    if (VE == 4)      ((uint2*)q)[0] = make_uint2(pack2(a0, a1), pack2(a2, a3));
    else if (VE == 2) ((u32*)q)[0] = pack2(a0, a1);
    else              *q = f2bf(a0);
}

// ---------------- MFMA GEMM: out[Mx256] = A[MxKA]@WA^T + X[MxKB]@WB^T + bias ----
// Block = 256 threads = 4 waves, tile 32 rows x 256 cols.
// Wave w: rows [16*(w&1), +16), cols [128*(w>>1), +128) = 8 N-tiles of 16.
// mfma_f32_16x16x32_bf16 layouts (HW-verified per guide):
//   A: lane holds A[m=lane&15][k=quad*8+j]   -> ds_read_b128 from LDS A-tile
//   B: lane holds B[k=quad*8+j][n=lane&15] = W[n][k] -> contiguous 16B global load
//   C/D: col=lane&15, row=quad*4+reg

template <int KA, int KB, bool RELU, bool OUT_BF16>
__global__ __launch_bounds__(256) void gemm_sage(const u16* __restrict__ A,
                                                 const u16* __restrict__ X,
                                                 const u16* __restrict__ WA,
                                                 const u16* __restrict__ WB,
                                                 const float* __restrict__ bias,
                                                 float* __restrict__ outF,
                                                 u16* __restrict__ outB, int M) {
    constexpr int KT = KA + KB;
    constexpr int STRIDE = KT + 8;  // +8 bf16 = +16B: keeps 16B align, breaks bank stride
    __shared__ __align__(16) u16 Alds[32 * STRIDE];

    const int tid = threadIdx.x;
    const int row0 = blockIdx.x * 32;

    // ---- stage A-tile (rows row0..row0+31): A into cols [0,KA), X into [KA,KT) ----
#pragma unroll
    for (int idx = tid; idx < 32 * KA / 8; idx += 256) {
        int r = idx / (KA / 8), c = (idx % (KA / 8)) * 8;
        int gr = row0 + r;
        uint4 v = make_uint4(0, 0, 0, 0);
        if (gr < M) v = *(const uint4*)(A + (size_t)gr * KA + c);
        *(uint4*)(&Alds[r * STRIDE + c]) = v;
    }
#pragma unroll
    for (int idx = tid; idx < 32 * KB / 8; idx += 256) {
        int r = idx / (KB / 8), c = (idx % (KB / 8)) * 8;
        int gr = row0 + r;
        uint4 v = make_uint4(0, 0, 0, 0);
        if (gr < M) v = *(const uint4*)(X + (size_t)gr * KB + c);
        *(uint4*)(&Alds[r * STRIDE + KA + c]) = v;
    }
    __syncthreads();

    const int lane = tid & 63;
    const int wid = tid >> 6;
    const int mrow = (wid & 1) * 16;
    const int nbase = (wid >> 1) * 128;
    const int ml = lane & 15;
    const int ql = lane >> 4;

    f32x4 acc[8];
#pragma unroll
    for (int t = 0; t < 8; t++) acc[t] = {0.f, 0.f, 0.f, 0.f};

    const u16* aptr = &Alds[(mrow + ml) * STRIDE + ql * 8];

#pragma unroll 2
    for (int k0 = 0; k0 < KA; k0 += 32) {
        bf16x8 af = *(const bf16x8*)(aptr + k0);
#pragma unroll
        for (int t = 0; t < 8; t++) {
            const u16* wp = WA + (size_t)(nbase + t * 16 + ml) * KA + k0 + ql * 8;
            bf16x8 bfg = *(const bf16x8*)wp;
            acc[t] = __builtin_amdgcn_mfma_f32_16x16x32_bf16(af, bfg, acc[t], 0, 0, 0);
        }
    }
#pragma unroll 2
    for (int k0 = 0; k0 < KB; k0 += 32) {
        bf16x8 af = *(const bf16x8*)(aptr + KA + k0);
#pragma unroll
        for (int t = 0; t < 8; t++) {
            const u16* wp = WB + (size_t)(nbase + t * 16 + ml) * KB + k0 + ql * 8;
            bf16x8 bfg = *(const bf16x8*)wp;
            acc[t] = __builtin_amdgcn_mfma_f32_16x16x32_bf16(af, bfg, acc[t], 0, 0, 0);
        }
    }

    // ---- epilogue ----
#pragma unroll
    for (int t = 0; t < 8; t++) {
        int colg = nbase + t * 16 + ml;
        float b = bias[colg];
#pragma unroll
        for (int r = 0; r < 4; r++) {
            int row = row0 + mrow + ql * 4 + r;
            if (row >= M) continue;
            float v = acc[t][r] + b;
            if (RELU) v = fmaxf(v, 0.f);
            if (OUT_BF16) outB[(size_t)row * HDIM + colg] = f2bf(v);
            else          outF[(size_t)row * HDIM + colg] = v;
        }
    }
}

// ---------------- host ----------------

extern "C" void kernel_launch(void* const* d_in, const int* in_sizes, int n_in,
                              void* d_out, int out_size, void* d_ws, size_t ws_size,
                              hipStream_t stream) {
    const float* x_user = (const float*)d_in[0];
    const float* x_item = (const float*)d_in[1];
    const int* eui_src = (const int*)d_in[2];
    const int* eui_dst = (const int*)d_in[3];
    const int* eiu_src = (const int*)d_in[4];
    const int* eiu_dst = (const int*)d_in[5];
    const float* W1l_ui = (const float*)d_in[6];
    const float* b1_ui  = (const float*)d_in[7];
    const float* W1r_ui = (const float*)d_in[8];
    const float* W1l_iu = (const float*)d_in[9];
    const float* b1_iu  = (const float*)d_in[10];
    const float* W1r_iu = (const float*)d_in[11];
    const float* W2l_ui = (const float*)d_in[12];
    const float* b2_ui  = (const float*)d_in[13];
    const float* W2r_ui = (const float*)d_in[14];
    const float* W2l_iu = (const float*)d_in[15];
    const float* b2_iu  = (const float*)d_in[16];
    const float* W2r_iu = (const float*)d_in[17];

    const int DU = 128, DI = 64;
    const int NU = in_sizes[0] / DU;   // 100000
    const int NI = in_sizes[1] / DI;   // 50000
    const int E  = in_sizes[2];        // 1600000

    // ---- carve workspace (256B aligned); total ~168.3 MB ----
    char* base = (char*)d_ws;
    size_t off = 0;
    auto carve = [&](size_t bytes) -> char* {
        char* p = base + off;
        off += (bytes + 255) & ~(size_t)255;
        return p;
    };
    int* cnt_i  = (int*)carve((size_t)NI * 4);
    int* cnt_u  = (int*)carve((size_t)NU * 4);
    int* rp_i   = (int*)carve((size_t)(NI + 1) * 4);
    int* rp_u   = (int*)carve((size_t)(NU + 1) * 4);
    int* col_ui = (int*)carve((size_t)E * 4);
    int* col_iu = (int*)carve((size_t)E * 4);
    int* bsum   = (int*)carve(1024 * 4);
    int* boff   = (int*)carve(1024 * 4);
    // bf16 weights
    u16* W1l_ui_b = (u16*)carve((size_t)HDIM * DU * 2);
    u16* W1r_ui_b = (u16*)carve((size_t)HDIM * DI * 2);
    u16* W1l_iu_b = (u16*)carve((size_t)HDIM * DI * 2);
    u16* W1r_iu_b = (u16*)carve((size_t)HDIM * DU * 2);
    u16* W2l_ui_b = (u16*)carve((size_t)HDIM * HDIM * 2);
    u16* W2r_ui_b = (u16*)carve((size_t)HDIM * HDIM * 2);
    u16* W2l_iu_b = (u16*)carve((size_t)HDIM * HDIM * 2);
    u16* W2r_iu_b = (u16*)carve((size_t)HDIM * HDIM * 2);
    // slot1 (25.6 MB): x_user_bf, later B_i (mean of h_user, [NI x 256])
    char* slot1 = carve((size_t)NU * DU * 2);          // == NI*HDIM*2
    u16* x_user_b = (u16*)slot1;
    u16* B_i      = (u16*)slot1;
    // slotB (51.2 MB): x_item_bf + A_i + A_u, later B_u ([NU x 256])
    char* slotB = carve((size_t)NU * HDIM * 2);
    u16* x_item_b = (u16*)slotB;                               // NI*64*2  = 6.4 MB
    u16* A_i      = (u16*)(slotB + (size_t)NI * DI * 2);       // NI*128*2 = 12.8 MB
    u16* A_u      = (u16*)(slotB + (size_t)NI * DI * 2 + (size_t)NI * DU * 2);  // NU*64*2
    u16* B_u      = (u16*)slotB;
    // h buffers (persist through layer 2)
    u16* h_item_b = (u16*)carve((size_t)NI * HDIM * 2);  // 25.6 MB
    u16* h_user_b = (u16*)carve((size_t)NU * HDIM * 2);  // 51.2 MB

    float* out_user = (float*)d_out;
    float* out_item = (float*)d_out + (size_t)NU * HDIM;

    // ---- CSR build ----
    hipMemsetAsync(cnt_i, 0, (size_t)NI * 4, stream);
    hipMemsetAsync(cnt_u, 0, (size_t)NU * 4, stream);
    int egrid = (E + 255) / 256;
    hist_kernel<<<egrid, 256, 0, stream>>>(eui_dst, E, cnt_i);
    hist_kernel<<<egrid, 256, 0, stream>>>(eiu_dst, E, cnt_u);
    int Bi = (NI + 1023) / 1024, Bu = (NU + 1023) / 1024;
    block_reduce_kernel<<<Bi, 256, 0, stream>>>(cnt_i, NI, bsum);
    scan_sums_kernel<<<1, 64, 0, stream>>>(bsum, boff, Bi);
    block_scan_write_kernel<<<Bi, 1024, 0, stream>>>(cnt_i, NI, boff, rp_i, cnt_i, E);
    fill_kernel<<<egrid, 256, 0, stream>>>(eui_src, eui_dst, E, cnt_i, col_ui);
    block_reduce_kernel<<<Bu, 256, 0, stream>>>(cnt_u, NU, bsum);
    scan_sums_kernel<<<1, 64, 0, stream>>>(bsum, boff, Bu);
    block_scan_write_kernel<<<Bu, 1024, 0, stream>>>(cnt_u, NU, boff, rp_u, cnt_u, E);
    fill_kernel<<<egrid, 256, 0, stream>>>(eiu_src, eiu_dst, E, cnt_u, col_iu);

    // ---- converts ----
    auto conv = [&](const float* in, u16* outp, size_t n) {
        int n4 = (int)(n / 4);
        f32_to_bf16_kernel<<<(n4 + 255) / 256, 256, 0, stream>>>(in, outp, n4);
    };
    conv(x_user, x_user_b, (size_t)NU * DU);
    conv(x_item, x_item_b, (size_t)NI * DI);
    conv(W1l_ui, W1l_ui_b, (size_t)HDIM * DU);
    conv(W1r_ui, W1r_ui_b, (size_t)HDIM * DI);
    conv(W1l_iu, W1l_iu_b, (size_t)HDIM * DI);
    conv(W1r_iu, W1r_iu_b, (size_t)HDIM * DU);
    conv(W2l_ui, W2l_ui_b, (size_t)HDIM * HDIM);
    conv(W2r_ui, W2r_ui_b, (size_t)HDIM * HDIM);
    conv(W2l_iu, W2l_iu_b, (size_t)HDIM * HDIM);
    conv(W2r_iu, W2r_iu_b, (size_t)HDIM * HDIM);

    // ---- layer 1 ----
    agg_mean<128><<<(NI + 3) / 4, 256, 0, stream>>>(x_user_b, rp_i, col_ui, A_i, NI);
    agg_mean<64> <<<(NU + 3) / 4, 256, 0, stream>>>(x_item_b, rp_u, col_iu, A_u, NU);
    gemm_sage<128, 64, true, true><<<(NI + 31) / 32, 256, 0, stream>>>(
        A_i, x_item_b, W1l_ui_b, W1r_ui_b, b1_ui, nullptr, h_item_b, NI);
    gemm_sage<64, 128, true, true><<<(NU + 31) / 32, 256, 0, stream>>>(
        A_u, x_user_b, W1l_iu_b, W1r_iu_b, b1_iu, nullptr, h_user_b, NU);

    // ---- layer 2 ----  (B_i overwrites x_user_b; B_u overwrites x_item/A_i/A_u: all dead)
    agg_mean<256><<<(NI + 3) / 4, 256, 0, stream>>>(h_user_b, rp_i, col_ui, B_i, NI);
    agg_mean<256><<<(NU + 3) / 4, 256, 0, stream>>>(h_item_b, rp_u, col_iu, B_u, NU);
    gemm_sage<256, 256, false, false><<<(NI + 31) / 32, 256, 0, stream>>>(
        B_i, h_item_b, W2l_ui_b, W2r_ui_b, b2_ui, out_item, nullptr, NI);
    gemm_sage<256, 256, false, false><<<(NU + 31) / 32, 256, 0, stream>>>(
        B_u, h_user_b, W2l_iu_b, W2r_iu_b, b2_iu, out_user, nullptr, NU);
}